// Round 4
// baseline (271.896 us; speedup 1.0000x reference)
//
#include <hip/hip_runtime.h>

#define H 8
#define NSEQ 4096
#define DIM 64
#define BATCH 8
#define AREV_LEN 4384   // 4096 lags + 288 zero pad (max read idx 4366). 4384 elems =
                        // 2192 dwords == 16 mod 32 -> shifted copy sits at bank
                        // offset +16 vs base copy: parity groups hit disjoint halves.
#define AREV_DW (AREV_LEN/2)   // 2192
#define XQ_HD 65536     // per-(h,d) xq elems: 128 tiles x [16 rows][32 s-elems].
                        // rows 0-7 = batches at s, rows 8-15 = batches at s-16
                        // (shift materialized -> B loads fully coalesced: quarter-wave
                        // reads 16 rows x 64B CONTIGUOUS = one 1KB transaction).
#define HD (H*DIM)      // 512

typedef __attribute__((ext_vector_type(8))) short short8;
typedef __attribute__((ext_vector_type(4))) float float4v;

__device__ inline unsigned short f32_to_bf16(float f) {
    unsigned int u = __float_as_uint(f);
    u += 0x7fffu + ((u >> 16) & 1u);   // RNE
    return (unsigned short)(u >> 16);
}

// ---- P1: arev[hd][i] = bf16( exp(clamp(log(gamma)*k + pos[k-1])) ) at k = 4095 - i ----
// (k==0 uses `zero`). Block (kb,h) also zeroes the pad of row d=kb (replaces memset).
__global__ __launch_bounds__(256) void build_arev(
    const float* __restrict__ zero, const float* __restrict__ pos,
    const float* __restrict__ gamma, unsigned short* __restrict__ arev)
{
    __shared__ float lg[64];
    __shared__ unsigned short T[64][65];
    int h = blockIdx.y, kb = blockIdx.x;
    int tid = threadIdx.x;
    if (tid < 64) lg[tid] = logf(gamma[h*64 + tid]);
    __syncthreads();
    #pragma unroll
    for (int jj = 0; jj < 16; ++jj) {
        int e = tid + 256*jj;
        int kk = e >> 6, dd = e & 63;
        int k = kb*64 + kk;
        float v;
        if (k == 0) v = zero[h*64 + dd];
        else        v = lg[dd] * (float)k + pos[(h*4095 + (k-1))*64 + dd];
        v = fminf(30.f, fmaxf(-60.f, v));
        T[kk][dd] = f32_to_bf16(expf(v));
    }
    __syncthreads();
    int i0 = 4032 - kb*64;   // tile writes arev[hd][i0 .. i0+63], i = 4095 - k
    #pragma unroll
    for (int jj = 0; jj < 16; ++jj) {
        int e = tid + 256*jj;
        int dpr = e >> 6, ii = e & 63;
        arev[(size_t)(h*64 + dpr)*AREV_LEN + i0 + ii] = T[63 - ii][dpr];
    }
    // zero pad region [4096, AREV_LEN) of row d = kb
    unsigned short* pr = arev + (size_t)(h*64 + kb)*AREV_LEN + 4096;
    for (int i = tid; i < AREV_LEN - 4096; i += 256) pr[i] = 0;
}

// ---- P2: xq[hd][s>>5][n][s&31] = bf16(x[n&7][h][s - 16*(n>>3)][d]) ----
// Tiled layout with the -16 shift materialized in rows 8-15 so GEMM B-loads are
// fully coalesced. float4 global loads, dword-packed stores (two copies).
__global__ __launch_bounds__(256) void build_xp(
    const float* __restrict__ x, unsigned short* __restrict__ xq)
{
    __shared__ unsigned short T[64][66];   // stride 66: dword-aligned, conflict-free cols
    int sb = blockIdx.x, h = blockIdx.y, b = blockIdx.z;
    int tid = threadIdx.x;
    const float4v* src4 =
        (const float4v*)(x + ((size_t)(b*H + h)*NSEQ + sb*64)*DIM);
    #pragma unroll
    for (int jj = 0; jj < 4; ++jj) {
        int e = tid + 256*jj;            // [0,1024)
        int ss = e >> 4, d4 = e & 15;
        float4v f = src4[ss*16 + d4];
        #pragma unroll
        for (int k = 0; k < 4; ++k) T[ss][4*d4 + k] = f32_to_bf16(f[k]);
    }
    __syncthreads();
    unsigned int* xq32 = (unsigned int*)xq;
    #pragma unroll
    for (int jj = 0; jj < 8; ++jj) {
        int e = tid + 256*jj;            // [0,2048)
        int dpr = e >> 5, c2 = e & 31;   // row d, dword col (2 s-elems)
        unsigned int lo = T[2*c2][dpr], hi2 = T[2*c2 + 1][dpr];
        unsigned int v = lo | (hi2 << 16);
        size_t base = (size_t)(h*64 + dpr) * XQ_HD;
        int s = sb*64 + 2*c2;
        xq32[(base + (size_t)(s >> 5)*512 + b*32 + (s & 31)) >> 1] = v;
        int s2 = s + 16;                 // shifted copy: row 8+b holds x at s'-16
        if (s2 < NSEQ)
            xq32[(base + (size_t)(s2 >> 5)*512 + (8 + b)*32 + (s2 & 31)) >> 1] = v;
    }
    if (sb == 0) {
        // front pad: rows 8+b, tile 0, elems [0,16) = x at negative s -> 0
        for (int e2 = tid; e2 < 64*8; e2 += 256) {
            int dd = e2 >> 3, c = e2 & 7;
            size_t base = (size_t)(h*64 + dd) * XQ_HD;
            xq32[((base + (8 + b)*32) >> 1) + c] = 0;
        }
    }
}

// ---- GEMM: per (h,d): Out[t, 0:8] = sum_s a[t-s] * X[s, 0:8], causal ----
// One WG = one (h,d) and a BAND PAIR {p, 3-p} of 1024-row t-bands; every wave
// does exactly 136 k-steps (zero imbalance). MFMA cols 0-7 (x unshifted) give
// odd 16-row strips, cols 8-15 (x pre-shifted -16 in xq rows 8-15) give even
// strips. A-ring with compile-time indices; depth-4 B register queue; B loads
// are single fully-coalesced 1KB/wave transactions from the tiled xq layout.
__global__ __launch_bounds__(256) void toeplitz_gemm(
    const unsigned short* __restrict__ arev,
    const unsigned short* __restrict__ xq,
    float* __restrict__ out)
{
    __shared__ unsigned int lds32[2*AREV_DW];  // [0]: arev dwords, [AREV_DW]: +1-elem shift

    // swizzle: 16 line-sharing consecutive-d WGs -> same XCD (id%8).
    int id = blockIdx.x;                 // [0, 1024)
    int q8 = id >> 7, rem = id & 127;
    int r  = rem >> 3, xx = rem & 7;
    int g  = q8*8 + xx;                  // [0, 64)
    int nlin = g*16 + r;                 // [0, 1024)
    int p  = nlin >> 9;                  // band pair: {p, 3-p}
    int h  = (nlin >> 6) & 7;
    int d  = nlin & 63;
    int hd = h*64 + d;

    int tid = threadIdx.x;
    const unsigned int* g32 = (const unsigned int*)(arev + (size_t)hd*AREV_LEN);
    int i0s = p << 9;                    // pair {1,2} never reads lag idx < 1024
    for (int i = i0s + tid; i < AREV_DW; i += 256) lds32[i] = g32[i];
    for (int i = i0s + tid; i < AREV_DW - 1; i += 256)
        lds32[AREV_DW + i] = (g32[i] >> 16) | (g32[i+1] << 16);  // elems 2i+1, 2i+2
    __syncthreads();

    int w = tid >> 6, lane = tid & 63;
    int nb = lane & 15;        // A-frag row m and B-frag col n
    int q  = lane >> 4;        // k-quad

    // B: lane (nb,q) reads xq[hd][s>>5][nb][8q..8q+7]: elem ofs = 16*s + nb*32 + 8q.
    const unsigned short* xrow = xq + (size_t)hd*XQ_HD + nb*32 + 8*q;
    int tsh = (nb >> 3) << 4;
    float* obase = out + ((size_t)((nb & 7)*H + h)*NSEQ)*DIM + d;

    auto run_phase = [&](int b) {
        float4v acc[8];
        #pragma unroll
        for (int j = 0; j < 8; ++j) acc[j] = (float4v){0.f,0.f,0.f,0.f};

        // A addressing: elem i0(j, s0) = B0 - 32j + s0 + 8q; s0 even => parity
        // is lane-constant: pick base copy (even) or +1-shift copy (odd) once.
        int B0  = 4095 - b - nb;
        int ofs = B0 + 8*q;
        int dwb = ((ofs & 1) ? AREV_DW : 0) + (ofs >> 1);
        auto LF = [&](int so) -> short8 {
            int dw = dwb + (so >> 1);    // so always even
            union { short8 v; unsigned int u[4]; } af;
            af.u[0] = lds32[dw];   af.u[1] = lds32[dw+1];
            af.u[2] = lds32[dw+2]; af.u[3] = lds32[dw+3];
            return af.v;
        };

        // ring: compile-time indices only (pure register renaming)
        short8 rg[8];
        #pragma unroll
        for (int j = 1; j < 8; ++j) rg[8 - j] = LF(-32*j);
        rg[0] = LF(0);

        int s_end = b + 240;   // multiple of 256

        // depth-4 B queue: bq[t&3] = B(32t); xq ofs = 16*s elems
        short8 bq[4];
        #pragma unroll
        for (int k = 0; k < 4; ++k)
            bq[k] = *reinterpret_cast<const short8*>(xrow + 512*k);

        for (int S = 0; S < s_end; S += 256) {
            #pragma unroll
            for (int u = 0; u < 8; ++u) {
                int so = S + 32*u;
                short8 rn = LF(so + 32);                       // A prefetch (depth 1)
                int sp = so + 128;                             // B prefetch (depth 4)
                if (sp > s_end - 32) sp = 0;                   // wave-uniform clamp
                short8 bn = *reinterpret_cast<const short8*>(xrow + (size_t)16*sp);
                short8 bcur = bq[u & 3];
                #pragma unroll
                for (int j = 7; j >= 0; --j)
                    acc[j] = __builtin_amdgcn_mfma_f32_16x16x32_bf16(
                        rg[(u - j) & 7], bcur, acc[j], 0, 0, 0);
                rg[(u + 1) & 7] = rn;   // slot freed by j=7 this step
                bq[u & 3] = bn;
            }
        }

        // C/D: col = lane&15, row(t within 16) = 4q + rr; sub-tile j at base b+32j,
        // cols 8-15 shifted down 16 rows.
        #pragma unroll
        for (int j = 0; j < 8; ++j) {
            #pragma unroll
            for (int rr = 0; rr < 4; ++rr) {
                int t = b - tsh + 32*j + 4*q + rr;
                obase[(size_t)t*DIM] = acc[j][rr];
            }
        }
    };

    // pair {p, 3-p}: wave w takes lo tile w, hi tile 3-w  => 136 k-steps each
    run_phase((p << 10)       + 256*w       + 16);
    run_phase(((3 - p) << 10) + 256*(3 - w) + 16);
}

extern "C" void kernel_launch(void* const* d_in, const int* in_sizes, int n_in,
                              void* d_out, int out_size, void* d_ws, size_t ws_size,
                              hipStream_t stream) {
    const float* x     = (const float*)d_in[0];
    const float* zero  = (const float*)d_in[1];
    const float* pos   = (const float*)d_in[2];
    const float* gamma = (const float*)d_in[3];
    float* out = (float*)d_out;

    unsigned short* arev = (unsigned short*)d_ws;                 // 512*4384*2 = 4.49 MB
    unsigned short* xq   = arev + (size_t)HD*AREV_LEN;            // 512*65536*2 = 67.1 MB

    build_arev<<<dim3(64, 8), 256, 0, stream>>>(zero, pos, gamma, arev);
    build_xp<<<dim3(64, 8, 8), 256, 0, stream>>>(x, xq);
    toeplitz_gemm<<<dim3(1024), 256, 0, stream>>>(arev, xq, out);
}

// Round 5
// 240.460 us; speedup vs baseline: 1.1307x; 1.1307x over previous
//
#include <hip/hip_runtime.h>

#define H 8
#define NSEQ 4096
#define DIM 64
#define BATCH 8
#define AREV_LEN 4384   // 4096 lags + 288 zero pad (max read idx 4374). 4384 elems =
                        // 2192 dwords == 16 mod 32 -> shifted copy sits at bank
                        // offset +16 vs base copy: parity groups hit disjoint halves.
#define AREV_DW (AREV_LEN/2)   // 2192
#define XPLEN 4144      // 16 front zeros (shifted-col reads) + 4096 + 32 tail pad.
                        // 8288 B/row, 16B-aligned. Max staged elem = 4112 (in-bounds).
#define HD (H*DIM)      // 512

typedef __attribute__((ext_vector_type(8))) short short8;
typedef __attribute__((ext_vector_type(4))) float float4v;
typedef const __attribute__((address_space(1))) unsigned int* gas_u32p;
typedef __attribute__((address_space(3))) unsigned int* las_u32p;

__device__ inline unsigned short f32_to_bf16(float f) {
    unsigned int u = __float_as_uint(f);
    u += 0x7fffu + ((u >> 16) & 1u);   // RNE
    return (unsigned short)(u >> 16);
}

// ---- P1: arev[hd][i] = bf16( exp(clamp(log(gamma)*k + pos[k-1])) ) at k = 4095 - i ----
__global__ __launch_bounds__(256) void build_arev(
    const float* __restrict__ zero, const float* __restrict__ pos,
    const float* __restrict__ gamma, unsigned short* __restrict__ arev)
{
    __shared__ float lg[64];
    __shared__ unsigned short T[64][65];
    int h = blockIdx.y, kb = blockIdx.x;
    int tid = threadIdx.x;
    if (tid < 64) lg[tid] = logf(gamma[h*64 + tid]);
    __syncthreads();
    #pragma unroll
    for (int jj = 0; jj < 16; ++jj) {
        int e = tid + 256*jj;
        int kk = e >> 6, dd = e & 63;
        int k = kb*64 + kk;
        float v;
        if (k == 0) v = zero[h*64 + dd];
        else        v = lg[dd] * (float)k + pos[(h*4095 + (k-1))*64 + dd];
        v = fminf(30.f, fmaxf(-60.f, v));
        T[kk][dd] = f32_to_bf16(expf(v));
    }
    __syncthreads();
    int i0 = 4032 - kb*64;   // tile writes arev[hd][i0 .. i0+63], i = 4095 - k
    #pragma unroll
    for (int jj = 0; jj < 16; ++jj) {
        int e = tid + 256*jj;
        int dpr = e >> 6, ii = e & 63;
        arev[(size_t)(h*64 + dpr)*AREV_LEN + i0 + ii] = T[63 - ii][dpr];
    }
    unsigned short* pr = arev + (size_t)(h*64 + kb)*AREV_LEN + 4096;
    for (int i = tid; i < AREV_LEN - 4096; i += 256) pr[i] = 0;
}

// ---- P2: xp[hd][b][16 + s] = bf16(x[b][h][s][d]); rows front/tail zero-padded ----
__global__ __launch_bounds__(256) void build_xp(
    const float* __restrict__ x, unsigned short* __restrict__ xp)
{
    __shared__ unsigned short T[64][66];   // stride 66: dword-aligned, conflict-free cols
    int sb = blockIdx.x, h = blockIdx.y, b = blockIdx.z;
    int tid = threadIdx.x;
    const float4v* src4 =
        (const float4v*)(x + ((size_t)(b*H + h)*NSEQ + sb*64)*DIM);
    #pragma unroll
    for (int jj = 0; jj < 4; ++jj) {
        int e = tid + 256*jj;            // [0,1024)
        int ss = e >> 4, d4 = e & 15;
        float4v f = src4[ss*16 + d4];
        #pragma unroll
        for (int k = 0; k < 4; ++k) T[ss][4*d4 + k] = f32_to_bf16(f[k]);
    }
    __syncthreads();
    unsigned int* xp32 = (unsigned int*)xp;
    #pragma unroll
    for (int jj = 0; jj < 8; ++jj) {
        int e = tid + 256*jj;            // [0,2048)
        int dpr = e >> 5, c2 = e & 31;   // row d, dword col (2 s-elems)
        unsigned int lo = T[2*c2][dpr], hi = T[2*c2 + 1][dpr];
        size_t dwofs = (((size_t)(h*64 + dpr)*BATCH + b)*XPLEN + 16 + sb*64) >> 1;
        xp32[dwofs + c2] = lo | (hi << 16);
    }
    if (sb == 0) {
        for (int e = tid; e < 64*16; e += 256) {
            int dd = e >> 4, i = e & 15;
            xp[((size_t)(h*64 + dd)*BATCH + b)*XPLEN + i] = 0;
        }
    }
    if (sb == 63) {
        for (int e = tid; e < 64*32; e += 256) {
            int dd = e >> 5, i = e & 31;
            xp[((size_t)(h*64 + dd)*BATCH + b)*XPLEN + 16 + NSEQ + i] = 0;
        }
    }
}

// ---- GEMM: per (h,d): Out[t, 0:8] = sum_s a[t-s] * X[s, 0:8], causal ----
// One WG = one (h,d) + band pair {p, 3-p}; 20 staged windows per block (equal
// for both pairs). Per 256-s window: stage next window's B tile (256 s x 16
// rows = 8KB) into double-buffered LDS via global_load_lds (issued at window
// top, drained by the window-end barrier ~1600 cyc later), then 8 k-steps of
// {1 A-ds_read (ring), 1 B-ds_read, 8 MFMA} -- ZERO vector-memory ops in the
// k-loop, so no per-step vmcnt waits. All 4 waves share the staged B tile
// (their s-ranges are nested); waves predicate off finished windows with a
// wave-uniform branch.
__global__ __launch_bounds__(256) void toeplitz_gemm(
    const unsigned short* __restrict__ arev,
    const unsigned short* __restrict__ xp,
    float* __restrict__ out)
{
    __shared__ unsigned int ldsA[2*AREV_DW];   // arev dwords + 1-elem-shift copy
    __shared__ unsigned int ldsB32[2*2048];    // 2 x 8KB B tiles: [chunk][row16][32 elems]

    // swizzle: 16 line-sharing consecutive-d WGs -> same XCD (id%8).
    int id = blockIdx.x;                 // [0, 1024)
    int q8 = id >> 7, rem = id & 127;
    int r  = rem >> 3, xx = rem & 7;
    int g  = q8*8 + xx;                  // [0, 64)
    int nlin = g*16 + r;                 // [0, 1024)
    int p  = nlin >> 9;                  // band pair: {p, 3-p}
    int h  = (nlin >> 6) & 7;
    int d  = nlin & 63;
    int hd = h*64 + d;

    int tid = threadIdx.x;
    const unsigned int* g32 = (const unsigned int*)(arev + (size_t)hd*AREV_LEN);
    int i0s = p << 9;                    // pair {1,2} never reads lag idx < 1024
    for (int i = i0s + tid; i < AREV_DW; i += 256) ldsA[i] = g32[i];
    for (int i = i0s + tid; i < AREV_DW - 1; i += 256)
        ldsA[AREV_DW + i] = (g32[i] >> 16) | (g32[i+1] << 16);  // elems 2i+1, 2i+2

    int w = tid >> 6, lane = tid & 63;
    int nb = lane & 15;        // A-frag row m and B-frag col n
    int q  = lane >> 4;        // k-quad
    int bq4 = nb*16 + q*4;     // B-frag dword offset within a 1KB chunk

    // staging: thread tid handles 16B pieces tid and tid+256 of the 8KB tile.
    // piece tid: chunk=tid>>6 (=w), row=(tid>>2)&15, sub=tid&3.
    int rowi = (tid >> 2) & 15;
    const unsigned short* xsrc =
        xp + ((size_t)hd*BATCH + (rowi & 7))*XPLEN + 16 - ((rowi >> 3) << 4)
           + w*32 + (tid & 3)*8;
    auto stage = [&](int buf, int S) {
        __builtin_amdgcn_global_load_lds(
            (gas_u32p)(const void*)(xsrc + S),
            (las_u32p)(void*)&ldsB32[buf*2048 + w*256], 16, 0, 0);
        __builtin_amdgcn_global_load_lds(
            (gas_u32p)(const void*)(xsrc + S + 128),
            (las_u32p)(void*)&ldsB32[buf*2048 + 1024 + w*256], 16, 0, 0);
    };

    const unsigned short* __restrict__ xp_keep = xp;  // (unused; silences warnings)
    (void)xp_keep;

    int tsh = (nb >> 3) << 4;
    float* obase = out + ((size_t)((nb & 7)*H + h)*NSEQ)*DIM + d;

    auto run_phase = [&](int b, int SWEEP, bool prestage_next) {
        float4v acc[8];
        #pragma unroll
        for (int j = 0; j < 8; ++j) acc[j] = (float4v){0.f,0.f,0.f,0.f};

        // A addressing: elem i0(j, s0) = B0 - 32j + s0 + 8q; s0 even => parity
        // lane-constant: base copy (even) or +1-shift copy (odd), chosen once.
        int B0  = 4095 - b - nb;
        int ofs = B0 + 8*q;
        int dwb = ((ofs & 1) ? AREV_DW : 0) + (ofs >> 1);
        auto LFA = [&](int so) -> short8 {
            int dw = dwb + (so >> 1);    // so always even
            union { short8 v; unsigned int u4[4]; } af;
            af.u4[0] = ldsA[dw];   af.u4[1] = ldsA[dw+1];
            af.u4[2] = ldsA[dw+2]; af.u4[3] = ldsA[dw+3];
            return af.v;
        };
        auto LFB = [&](int buf, int u) -> short8 {
            int dwi = buf*2048 + u*256 + bq4;
            union { short8 v; unsigned int u4[4]; } bf_;
            bf_.u4[0] = ldsB32[dwi];   bf_.u4[1] = ldsB32[dwi+1];
            bf_.u4[2] = ldsB32[dwi+2]; bf_.u4[3] = ldsB32[dwi+3];
            return bf_.v;
        };

        // ring: compile-time indices only (pure register renaming)
        short8 rg[8];
        #pragma unroll
        for (int j = 1; j < 8; ++j) rg[8 - j] = LFA(-32*j);
        rg[0] = LFA(0);

        int s_end = b + 240;   // multiple of 256; <= SWEEP
        int cur = 0;
        for (int S = 0; S < SWEEP; S += 256) {
            if (S + 256 < SWEEP) stage(cur ^ 1, S + 256);
            if (S < s_end) {               // wave-uniform predicate
                short8 bf = LFB(cur, 0);
                #pragma unroll
                for (int u = 0; u < 8; ++u) {
                    short8 rn = LFA(S + 32*u + 32);   // A prefetch (ring feed)
                    short8 bn = bf;
                    if (u < 7) bn = LFB(cur, u + 1);  // B prefetch (next step)
                    #pragma unroll
                    for (int j = 7; j >= 0; --j)
                        acc[j] = __builtin_amdgcn_mfma_f32_16x16x32_bf16(
                            rg[(u - j) & 7], bf, acc[j], 0, 0, 0);
                    rg[(u + 1) & 7] = rn;   // slot freed by j=7 this step
                    bf = bn;
                }
            }
            __syncthreads();   // drains this window's glds; next tile ready
            cur ^= 1;
        }
        if (prestage_next) stage(0, 0);    // overlap next phase's first tile

        // C/D: col = lane&15, row(t within 16) = 4q + rr; sub-tile j at base
        // b+32j, cols 8-15 shifted down 16 rows.
        #pragma unroll
        for (int j = 0; j < 8; ++j) {
            #pragma unroll
            for (int rr = 0; rr < 4; ++rr) {
                int t = b - tsh + 32*j + 4*q + rr;
                obase[(size_t)t*DIM] = acc[j][rr];
            }
        }
        if (prestage_next) __syncthreads();  // buf0 ready + ordered for next phase
    };

    stage(0, 0);          // first tile of phase 1
    __syncthreads();      // covers ldsA writes + first glds

    // pair {p, 3-p}: wave w takes lo tile w, hi tile 3-w; sweeps sized to the
    // block max s_end so barrier counts match (20 windows total either pair).
    run_phase((p << 10)       + 256*w       + 16, (p + 1) << 10, true);
    run_phase(((3 - p) << 10) + 256*(3 - w) + 16, (4 - p) << 10, false);
}

extern "C" void kernel_launch(void* const* d_in, const int* in_sizes, int n_in,
                              void* d_out, int out_size, void* d_ws, size_t ws_size,
                              hipStream_t stream) {
    const float* x     = (const float*)d_in[0];
    const float* zero  = (const float*)d_in[1];
    const float* pos   = (const float*)d_in[2];
    const float* gamma = (const float*)d_in[3];
    float* out = (float*)d_out;

    unsigned short* arev = (unsigned short*)d_ws;                 // 512*4384*2 = 4.49 MB
    unsigned short* xp   = arev + (size_t)HD*AREV_LEN;            // 512*8*4144*2 = 33.9 MB

    build_arev<<<dim3(64, 8), 256, 0, stream>>>(zero, pos, gamma, arev);
    build_xp<<<dim3(64, 8, 8), 256, 0, stream>>>(x, xp);
    toeplitz_gemm<<<dim3(1024), 256, 0, stream>>>(arev, xp, out);
}